// Round 2
// baseline (75.232 us; speedup 1.0000x reference)
//
#include <hip/hip_runtime.h>
#include <math.h>

// Bit-exact-to-numpy float32 helpers: block fp contraction (HIP defaults to
// -ffp-contract=fast; an fma vs mul+add 1-ulp difference can flip the
// ns=ceil(seg/0.2) quantization or the ld>=0 / vt1>=0 light-hit decisions).
// DECISION CHAIN IS FROZEN: a,b,disc,x1,x2,seg,ns,step,t,pc,lb,lc,ld,lsq,vt1
// replicate the reference op-for-op; only bitwise-identity simplifications
// are allowed. __expf feeds continuous outputs only.
__device__ __forceinline__ float fmulr(float a, float b) { return __fmul_rn(a, b); }
__device__ __forceinline__ float faddr(float a, float b) { return __fadd_rn(a, b); }
__device__ __forceinline__ float fsubr(float a, float b) { return __fsub_rn(a, b); }

struct Col { float x, y, z; };

// ---- Scalar specialized path (tail / reference use): round-0 proven body ----
__device__ __forceinline__ Col shade1(float rdx, float rdy, float rdz)
{
    const float BGx = 0.572f, BGy = 0.772f, BGz = 0.921f;
    Col out = {BGx, BGy, BGz};

    float a = faddr(faddr(fmulr(rdx, rdx), fmulr(rdy, rdy)), fmulr(rdz, rdz));
    float b = fmulr(2.0f, fmulr(rdz, 3.0f));
    float disc = fsubr(fmulr(b, b), fmulr(fmulr(4.0f, a), 8.0f));
    if (disc < 0.0f) return out;

    float sq = sqrtf(disc > 0.0f ? disc : 1.0f);
    float twoa = fmulr(2.0f, a);
    float x2 = faddr(-b, sq) / twoa;
    if (x2 < 0.0f) return out;
    float x1 = fsubr(-b, sq) / twoa;

    float t0 = fmaxf(x1, 0.0f);
    float t1 = x2;
    float seg = fsubr(t1, t0);
    float ns = ceilf(seg / 0.2f);
    float step = seg / fmaxf(ns, 1.0f);
    int nsi = (int)fminf(ns, 12.0f);

    float acc = 0.0f;
    for (int k = 0; k < nsi; ++k) {
        float t = fsubr(t1, fmulr((float)k + 0.5f, step));
        float pcx = fmulr(t, rdx);
        float pcy = fmulr(t, rdy);
        float pcz = faddr(3.0f, fmulr(t, rdz));
        float lb = fmulr(2.0f, pcy);
        float lc = fsubr(faddr(faddr(fmulr(pcx, pcx), fmulr(pcy, pcy)), fmulr(pcz, pcz)), 1.0f);
        float ld = fsubr(fmulr(lb, lb), fmulr(4.0f, lc));
        if (ld >= 0.0f) {
            float lsq = sqrtf(ld > 0.0f ? ld : 1.0f);
            float vt1 = fmulr(faddr(-lb, lsq), 0.5f);
            if (vt1 >= 0.0f) acc += __expf(-1.2f * vt1);
        }
    }

    float sn  = __expf(-0.6f * (step * ns));
    float sn1 = __expf(-0.6f * (step * (ns + 1.0f)));
    float result = 0.6f * step * sn1 * acc;
    out.x = BGx * sn + 1.3f * result;
    out.y = BGy * sn + 0.3f * result;
    out.z = BGz * sn + 0.9f * result;
    return out;
}

// ---- Generic fallback (any scene). __noinline__: keep its registers out of
// the hot path; never taken for the benched scene.
__device__ __noinline__ Col shadeg(float rdx, float rdy, float rdz,
                                   float cx, float cy, float cz,
                                   float rr, float ocx, float ocy, float ocz,
                                   float cc)
{
    const float BGx = 0.572f, BGy = 0.772f, BGz = 0.921f;
    Col out = {BGx, BGy, BGz};

    float a = faddr(faddr(fmulr(rdx, rdx), fmulr(rdy, rdy)), fmulr(rdz, rdz));
    float b = fmulr(2.0f, faddr(faddr(fmulr(rdx, ocx), fmulr(rdy, ocy)), fmulr(rdz, ocz)));
    float disc = fsubr(fmulr(b, b), fmulr(fmulr(4.0f, a), cc));
    if (disc < 0.0f) return out;

    float sq = sqrtf(disc > 0.0f ? disc : 1.0f);
    float twoa = fmulr(2.0f, a);
    float x2 = faddr(-b, sq) / twoa;
    if (x2 < 0.0f) return out;
    float x1 = fsubr(-b, sq) / twoa;

    float t0 = fmaxf(x1, 0.0f);
    float t1 = x2;
    float seg = fsubr(t1, t0);
    float ns = ceilf(seg / 0.2f);
    float step = seg / fmaxf(ns, 1.0f);
    int nsi = (int)fminf(ns, 12.0f);

    float acc = 0.0f;
    for (int k = 0; k < nsi; ++k) {
        float t = fsubr(t1, fmulr((float)k + 0.5f, step));
        float pcx = fsubr(faddr(0.0f, fmulr(t, rdx)), cx);
        float pcy = fsubr(faddr(0.0f, fmulr(t, rdy)), cy);
        float pcz = fsubr(faddr(3.0f, fmulr(t, rdz)), cz);
        float lb = fmulr(2.0f, pcy);
        float lc = fsubr(faddr(faddr(fmulr(pcx, pcx), fmulr(pcy, pcy)), fmulr(pcz, pcz)), rr);
        float ld = fsubr(fmulr(lb, lb), fmulr(4.0f, lc));
        if (ld >= 0.0f) {
            float lsq = sqrtf(ld > 0.0f ? ld : 1.0f);
            float vt1 = fmulr(faddr(-lb, lsq), 0.5f);
            if (vt1 >= 0.0f) acc += __expf(-1.2f * vt1);
        }
    }

    float sn  = __expf(-0.6f * (step * ns));
    float sn1 = __expf(-0.6f * (step * (ns + 1.0f)));
    float result = 0.6f * step * sn1 * acc;
    out.x = BGx * sn + 1.3f * result;
    out.y = BGy * sn + 0.3f * result;
    out.z = BGz * sn + 0.9f * result;
    return out;
}

// 4 pixels/thread, float4-vectorized I/O, interleaved inner loop.
// Memory instructions per 4 pixels: 3 loads + 3 stores (vs 12+12 scalar).
// Cross-pixel ILP-4 in the sample loop; all-miss threads exit early.
__global__ __launch_bounds__(256)
void raymarch4_kernel(const float* __restrict__ scene,
                      const float* __restrict__ dirs,
                      float* __restrict__ out,
                      int npix)
{
    const float BGx = 0.572f, BGy = 0.772f, BGz = 0.921f;

    int t = blockIdx.x * blockDim.x + threadIdx.x;
    int p0 = 4 * t;
    if (p0 >= npix) return;

    // Uniform scalar loads + uniform branch (s_cbranch, no divergence).
    float cx = scene[0], cy = scene[1], cz = scene[2], r = scene[3];
    bool special = (cx == 0.0f && cy == 0.0f && cz == 0.0f && r == 1.0f);

    if (special && (p0 + 3 < npix)) {
        // ---- fast path: center=(0,0,0), radius=1, 4 whole pixels ----
        const float4* d4 = (const float4*)dirs;  // 16B-aligned: 48*t % 16 == 0
        float4 A = d4[3 * t + 0];
        float4 B = d4[3 * t + 1];
        float4 C = d4[3 * t + 2];
        float rdx[4] = {A.x, A.w, B.z, C.y};
        float rdy[4] = {A.y, B.x, B.w, C.z};
        float rdz[4] = {A.z, B.y, C.x, C.w};

        float t1[4], stp[4], nsf[4], acc[4];
        int nsi[4];
        bool hit[4];

        #pragma unroll
        for (int j = 0; j < 4; ++j) {
            float a = faddr(faddr(fmulr(rdx[j], rdx[j]), fmulr(rdy[j], rdy[j])), fmulr(rdz[j], rdz[j]));
            float b = fmulr(2.0f, fmulr(rdz[j], 3.0f));
            float disc = fsubr(fmulr(b, b), fmulr(fmulr(4.0f, a), 8.0f));
            float sq = sqrtf(disc > 0.0f ? disc : 1.0f);   // IEEE sqrt (frozen)
            float twoa = fmulr(2.0f, a);
            float x2 = faddr(-b, sq) / twoa;               // IEEE div (frozen)
            float x1 = fsubr(-b, sq) / twoa;
            bool h = (disc >= 0.0f) & (x2 >= 0.0f);        // == reference hit mask
            float t0 = fmaxf(x1, 0.0f);
            float seg = fsubr(x2, t0);                     // >= 0 always
            float ns = ceilf(seg / 0.2f);                  // frozen quantization
            float st = seg / fmaxf(ns, 1.0f);
            t1[j] = x2; stp[j] = st; nsf[j] = ns;
            nsi[j] = h ? (int)fminf(ns, 12.0f) : 0;        // miss => 0 iterations
            hit[j] = h; acc[j] = 0.0f;
        }

        // All-miss: pure background, skip loop + epilogue exps.
        if (!(hit[0] | hit[1] | hit[2] | hit[3])) {
            float4 O0 = {BGx, BGy, BGz, BGx};
            float4 O1 = {BGy, BGz, BGx, BGy};
            float4 O2 = {BGz, BGx, BGy, BGz};
            float4* o4 = (float4*)out;
            o4[3 * t + 0] = O0; o4[3 * t + 1] = O1; o4[3 * t + 2] = O2;
            return;
        }

        int kmax = max(max(nsi[0], nsi[1]), max(nsi[2], nsi[3]));
        for (int k = 0; k < kmax; ++k) {
            float kf = faddr((float)k, 0.5f);              // exact for k<=11
            #pragma unroll
            for (int j = 0; j < 4; ++j) {
                // Per-pixel body is op-for-op the round-0 sequence; inactive
                // lanes/pixels add +0.0f (exact for acc>=+0). Selected exp
                // values are always finite (vt1>=0 => arg<=0).
                float tt  = fsubr(t1[j], fmulr(kf, stp[j]));
                float pcx = fmulr(tt, rdx[j]);
                float pcy = fmulr(tt, rdy[j]);
                float pcz = faddr(3.0f, fmulr(tt, rdz[j]));
                float lb  = fmulr(2.0f, pcy);
                float lc  = fsubr(faddr(faddr(fmulr(pcx, pcx), fmulr(pcy, pcy)), fmulr(pcz, pcz)), 1.0f);
                float ld  = fsubr(fmulr(lb, lb), fmulr(4.0f, lc));
                float lsq = sqrtf(ld > 0.0f ? ld : 1.0f);  // IEEE; feeds frozen vt1>=0
                float vt1 = fmulr(faddr(-lb, lsq), 0.5f);
                bool act  = (k < nsi[j]) & (ld >= 0.0f) & (vt1 >= 0.0f);
                acc[j] = faddr(acc[j], act ? __expf(-1.2f * vt1) : 0.0f);
            }
        }

        float o[12];
        #pragma unroll
        for (int j = 0; j < 4; ++j) {
            float sn  = __expf(-0.6f * (stp[j] * nsf[j]));          // continuous only
            float sn1 = __expf(-0.6f * (stp[j] * (nsf[j] + 1.0f)));
            float result = 0.6f * stp[j] * sn1 * acc[j];
            float ox = BGx * sn + 1.3f * result;
            float oy = BGy * sn + 0.3f * result;
            float oz = BGz * sn + 0.9f * result;
            o[3 * j + 0] = hit[j] ? ox : BGx;   // reference: where(hit, color, BG)
            o[3 * j + 1] = hit[j] ? oy : BGy;
            o[3 * j + 2] = hit[j] ? oz : BGz;
        }
        float4 O0 = {o[0], o[1], o[2],  o[3]};
        float4 O1 = {o[4], o[5], o[6],  o[7]};
        float4 O2 = {o[8], o[9], o[10], o[11]};
        float4* o4 = (float4*)out;
        o4[3 * t + 0] = O0; o4[3 * t + 1] = O1; o4[3 * t + 2] = O2;
        return;
    }

    // ---- slow path: generic scene and/or tail pixels, scalar ----
    float rr = fmulr(r, r);
    float ocx = fsubr(0.0f, cx);
    float ocy = fsubr(0.0f, cy);
    float ocz = fsubr(3.0f, cz);
    float cc = fsubr(faddr(faddr(fmulr(ocx, ocx), fmulr(ocy, ocy)), fmulr(ocz, ocz)), rr);

    for (int j = 0; j < 4; ++j) {
        int p = p0 + j;
        if (p >= npix) break;
        float rdx = dirs[3 * p + 0];
        float rdy = dirs[3 * p + 1];
        float rdz = dirs[3 * p + 2];
        Col c = special ? shade1(rdx, rdy, rdz)
                        : shadeg(rdx, rdy, rdz, cx, cy, cz, rr, ocx, ocy, ocz, cc);
        out[3 * p + 0] = c.x;
        out[3 * p + 1] = c.y;
        out[3 * p + 2] = c.z;
    }
}

extern "C" void kernel_launch(void* const* d_in, const int* in_sizes, int n_in,
                              void* d_out, int out_size, void* d_ws, size_t ws_size,
                              hipStream_t stream) {
    const float* scene = (const float*)d_in[0];   // [1,4]: cx,cy,cz,r
    const float* dirs  = (const float*)d_in[1];   // [1024,1024,3] float32
    float* out = (float*)d_out;                   // [1024,1024,3] float32

    int npix = in_sizes[1] / 3;
    int nthreads = (npix + 3) / 4;
    dim3 block(256);
    dim3 grid((nthreads + 255) / 256);
    raymarch4_kernel<<<grid, block, 0, stream>>>(scene, dirs, out, npix);
}